// Round 4
// baseline (950.230 us; speedup 1.0000x reference)
//
#include <hip/hip_runtime.h>
#include <math.h>

// Problem constants (fixed by the reference)
#define B_N  16384
#define T_N  3
#define D_N  512
#define G_N  4
#define NE_N 4
#define H_N  512
#define E_N  256
#define GH_N 256
#define K16  16      // G*NE experts
#define TH_N 128
#define TO_N 64

typedef __attribute__((ext_vector_type(8))) short short8;
typedef __attribute__((ext_vector_type(4))) float floatx4;

__device__ __forceinline__ unsigned short f2bf(float f) {
    union { float f; unsigned u; } v; v.f = f;
    unsigned r = (v.u + 0x7fffu + ((v.u >> 16) & 1u)) >> 16;
    return (unsigned short)r;
}
__device__ __forceinline__ float bf2f(unsigned short h) {
    union { unsigned u; float f; } v; v.u = ((unsigned)h) << 16;
    return v.f;
}
__device__ __forceinline__ unsigned pack2(float lo, float hi) {
    return ((unsigned)f2bf(hi) << 16) | (unsigned)f2bf(lo);
}

typedef const __attribute__((address_space(1))) void gvoid_t;
typedef __attribute__((address_space(3))) void lvoid_t;

#if __has_builtin(__builtin_amdgcn_global_load_lds)
#define HAVE_GLL 1
__device__ __forceinline__ void load_lds16(const void* g, void* l) {
    __builtin_amdgcn_global_load_lds((gvoid_t*)g, (lvoid_t*)l, 16, 0, 0);
}
#else
#define HAVE_GLL 0
#endif

// ---------------------------------------------------------------------------
// Input cast: x -> bf16 [BC][G*D]; gin = x[:,1+t]+x[:,0] -> bf16 [BC][T*D]
// ---------------------------------------------------------------------------
__global__ __launch_bounds__(256) void convert_inputs(
    const float* __restrict__ x, unsigned short* __restrict__ xb,
    unsigned short* __restrict__ ginb)
{
    const long b = blockIdx.x;
    const int tid = threadIdx.x;           // 256 threads, 2 floats each per g
    const float* xr = x + b * (G_N * D_N);
    unsigned short* xo = xb + b * (G_N * D_N);
    unsigned short* go = ginb + b * (T_N * D_N);
    float2 v0 = *(const float2*)&xr[tid * 2];
    *(unsigned*)&xo[tid * 2] = pack2(v0.x, v0.y);
    #pragma unroll
    for (int g = 1; g < G_N; ++g) {
        float2 v = *(const float2*)&xr[g * D_N + tid * 2];
        *(unsigned*)&xo[g * D_N + tid * 2] = pack2(v.x, v.y);
        *(unsigned*)&go[(g - 1) * D_N + tid * 2] = pack2(v.x + v0.x, v.y + v0.y);
    }
}

// ---------------------------------------------------------------------------
// Weight transpose + cast: in fp32 [Z][K][N] -> out bf16 [Z][N][K]
// ---------------------------------------------------------------------------
__global__ __launch_bounds__(256) void transpose_w(
    const float* __restrict__ in, unsigned short* __restrict__ out, int K, int N)
{
    __shared__ float tile[32][33];
    const int tx = threadIdx.x, ty = threadIdx.y;      // block (32,8)
    const long zo = (long)blockIdx.z * K * N;
    const int n0 = blockIdx.x * 32, k0 = blockIdx.y * 32;
    #pragma unroll
    for (int i = 0; i < 4; ++i)
        tile[ty + 8 * i][tx] = in[zo + (long)(k0 + ty + 8 * i) * N + n0 + tx];
    __syncthreads();
    #pragma unroll
    for (int i = 0; i < 4; ++i)
        out[zo + (long)(n0 + ty + 8 * i) * K + k0 + tx] = f2bf(tile[tx][ty + 8 * i]);
}

// ---------------------------------------------------------------------------
// Fused expert MLP: per block = one (g,n) expert, 128 batch rows, all E=256.
//   hc-loop (4 x 128 H-cols):
//     stage1: h1c[128][128] = relu(X[128x512] @ W1[:,hc] + b1)  (MFMA, K=512)
//     stage2: acc2[128][256] += h1c @ W2[hc,:]                  (MFMA, K=128)
//   epilogue: emb = acc2 + b2 (bf16)
// Removes the h1 HBM round-trip entirely.
// ---------------------------------------------------------------------------
__global__ __launch_bounds__(256) void expert_fused(
    const unsigned short* __restrict__ xb,   // [BC][2048]
    const unsigned short* __restrict__ W1t,  // [16][512 h][512 d]
    const float* __restrict__ eb1,           // [16][512]
    const unsigned short* __restrict__ W2t,  // [16][256 e][512 h]
    const float* __restrict__ eb2,           // [16][256]
    unsigned short* __restrict__ emb)        // [BC][16*256]
{
    __shared__ __align__(16) unsigned short sm[33792];   // 66 KB
    unsigned short* As  = sm;            // [128][32]
    unsigned short* Bs1 = sm + 4096;     // [128][32]
    unsigned short* Bs2 = sm + 8192;     // [256][32]
    unsigned short* th  = sm + 16384;    // [128][136]  (+8 pad kills bank conflicts)
    const int tid = threadIdx.x;
    const int z = blockIdx.y;            // g*4+n
    const int g = z >> 2;
    const long m0 = (long)blockIdx.x * 128;
    const unsigned short* Ab  = xb + m0 * 2048 + g * 512;
    const unsigned short* B1b = W1t + (long)z * 262144;
    const unsigned short* B2b = W2t + (long)z * 131072;
    const int lane16 = tid & 15;
    const int quad = (tid & 63) >> 4;
    const int wave = tid >> 6;
    const int wm  = (wave >> 1) * 64;    // stage1+2 row offset
    const int wn  = (wave & 1) * 64;     // stage1 col offset (within 128 h-chunk)
    const int wn2 = (wave & 1) * 128;    // stage2 col offset (within 256 E)
    const int srow = tid >> 2;           // staging row (0..63)
    const int scol = (tid & 3) * 8;      // staging col

    floatx4 acc2[4][8] = {};

    #pragma unroll 1
    for (int hc = 0; hc < 4; ++hc) {
        const unsigned short* B1h = B1b + (long)hc * 128 * 512;
        floatx4 acc1[4][4] = {};

        // ---- stage 1: [128x512] @ [512x128] (K-loop) ----
        for (int k0 = 0; k0 < 512; k0 += 32) {
#if HAVE_GLL
            load_lds16(Ab + (long)srow * 2048 + k0 + scol, &As[tid * 8]);
            load_lds16(Ab + (long)(srow + 64) * 2048 + k0 + scol, &As[2048 + tid * 8]);
            load_lds16(B1h + (long)srow * 512 + k0 + scol, &Bs1[tid * 8]);
            load_lds16(B1h + (long)(srow + 64) * 512 + k0 + scol, &Bs1[2048 + tid * 8]);
#else
            *(uint4*)&As[tid * 8] = *(const uint4*)(Ab + (long)srow * 2048 + k0 + scol);
            *(uint4*)&As[2048 + tid * 8] = *(const uint4*)(Ab + (long)(srow + 64) * 2048 + k0 + scol);
            *(uint4*)&Bs1[tid * 8] = *(const uint4*)(B1h + (long)srow * 512 + k0 + scol);
            *(uint4*)&Bs1[2048 + tid * 8] = *(const uint4*)(B1h + (long)(srow + 64) * 512 + k0 + scol);
#endif
            __syncthreads();
            short8 a[4], b[4];
            #pragma unroll
            for (int mi = 0; mi < 4; ++mi)
                a[mi] = *(const short8*)&As[(wm + mi * 16 + lane16) * 32 + quad * 8];
            #pragma unroll
            for (int ni = 0; ni < 4; ++ni)
                b[ni] = *(const short8*)&Bs1[(wn + ni * 16 + lane16) * 32 + quad * 8];
            #pragma unroll
            for (int mi = 0; mi < 4; ++mi)
                #pragma unroll
                for (int ni = 0; ni < 4; ++ni)
                    acc1[mi][ni] = __builtin_amdgcn_mfma_f32_16x16x32_bf16(
                        a[mi], b[ni], acc1[mi][ni], 0, 0, 0);
            __syncthreads();
        }

        // ---- epilogue 1: bias + relu -> th (padded LDS) ----
        #pragma unroll
        for (int mi = 0; mi < 4; ++mi) {
            #pragma unroll
            for (int ni = 0; ni < 4; ++ni) {
                const int col = wn + ni * 16 + lane16;
                const float bv = eb1[z * 512 + hc * 128 + col];
                #pragma unroll
                for (int r = 0; r < 4; ++r) {
                    const int row = wm + mi * 16 + quad * 4 + r;
                    th[row * 136 + col] = f2bf(fmaxf(acc1[mi][ni][r] + bv, 0.0f));
                }
            }
        }

        // ---- stage 2: acc2 += th[128x128] @ W2chunk[128x256] ----
        #pragma unroll 1
        for (int kk = 0; kk < 4; ++kk) {
            #pragma unroll
            for (int it = 0; it < 4; ++it) {
                const int seg = it * 256 + tid;
                const int r = seg >> 2, c8 = (seg & 3) * 8;
#if HAVE_GLL
                load_lds16(B2b + (long)r * 512 + hc * 128 + kk * 32 + c8, &Bs2[seg * 8]);
#else
                *(uint4*)&Bs2[seg * 8] =
                    *(const uint4*)(B2b + (long)r * 512 + hc * 128 + kk * 32 + c8);
#endif
            }
            __syncthreads();   // covers th visibility (kk==0) + Bs2 staging
            short8 a2[4], b2[8];
            #pragma unroll
            for (int mi = 0; mi < 4; ++mi)
                a2[mi] = *(const short8*)&th[(wm + mi * 16 + lane16) * 136 + kk * 32 + quad * 8];
            #pragma unroll
            for (int ni = 0; ni < 8; ++ni)
                b2[ni] = *(const short8*)&Bs2[(wn2 + ni * 16 + lane16) * 32 + quad * 8];
            #pragma unroll
            for (int mi = 0; mi < 4; ++mi)
                #pragma unroll
                for (int ni = 0; ni < 8; ++ni)
                    acc2[mi][ni] = __builtin_amdgcn_mfma_f32_16x16x32_bf16(
                        a2[mi], b2[ni], acc2[mi][ni], 0, 0, 0);
            __syncthreads();
        }
    }

    // ---- final epilogue: emb = acc2 + b2 (bf16) ----
    unsigned short* Eb = emb + m0 * 4096 + z * 256;
    #pragma unroll
    for (int mi = 0; mi < 4; ++mi) {
        #pragma unroll
        for (int ni = 0; ni < 8; ++ni) {
            const int col = wn2 + ni * 16 + lane16;
            const float bv = eb2[z * 256 + col];
            #pragma unroll
            for (int r = 0; r < 4; ++r) {
                const int row = wm + mi * 16 + quad * 4 + r;
                Eb[(long)row * 4096 + col] = f2bf(acc2[mi][ni][r] + bv);
            }
        }
    }
}

// ---------------------------------------------------------------------------
// bf16 MFMA GEMM (used for gate layer 1): C = relu(A @ Bt^T + bias)
// ---------------------------------------------------------------------------
template<int RELU>
__global__ __launch_bounds__(256) void gemm_bf16(
    const unsigned short* __restrict__ A, int lda, int a_zoff,
    const unsigned short* __restrict__ Bt, int bt_zoff,
    const float* __restrict__ bias, int bias_zoff,
    unsigned short* __restrict__ C, int ldc, int c_zoff, int K)
{
    __shared__ __align__(16) unsigned short As[128 * 32];
    __shared__ __align__(16) unsigned short Bs[128 * 32];
    const int tid = threadIdx.x;
    const int z = blockIdx.z;
    const long m0 = (long)blockIdx.x * 128;
    const long n0 = (long)blockIdx.y * 128;
    const unsigned short* Ab = A + (long)z * a_zoff + m0 * lda;
    const unsigned short* Bb = Bt + (long)z * bt_zoff + n0 * K;
    const int lane16 = tid & 15;
    const int quad = (tid & 63) >> 4;
    const int wave = tid >> 6;
    const int wm = (wave >> 1) * 64;
    const int wn = (wave & 1) * 64;
    const int srow = tid >> 2;
    const int scol = (tid & 3) * 8;

    floatx4 acc[4][4] = {};

    for (int k0 = 0; k0 < K; k0 += 32) {
#if HAVE_GLL
        load_lds16(Ab + (long)srow * lda + k0 + scol, &As[tid * 8]);
        load_lds16(Ab + (long)(srow + 64) * lda + k0 + scol, &As[2048 + tid * 8]);
        load_lds16(Bb + (long)srow * K + k0 + scol, &Bs[tid * 8]);
        load_lds16(Bb + (long)(srow + 64) * K + k0 + scol, &Bs[2048 + tid * 8]);
#else
        *(uint4*)&As[tid * 8] = *(const uint4*)(Ab + (long)srow * lda + k0 + scol);
        *(uint4*)&As[2048 + tid * 8] = *(const uint4*)(Ab + (long)(srow + 64) * lda + k0 + scol);
        *(uint4*)&Bs[tid * 8] = *(const uint4*)(Bb + (long)srow * K + k0 + scol);
        *(uint4*)&Bs[2048 + tid * 8] = *(const uint4*)(Bb + (long)(srow + 64) * K + k0 + scol);
#endif
        __syncthreads();
        short8 a[4], b[4];
        #pragma unroll
        for (int mi = 0; mi < 4; ++mi)
            a[mi] = *(const short8*)&As[(wm + mi * 16 + lane16) * 32 + quad * 8];
        #pragma unroll
        for (int ni = 0; ni < 4; ++ni)
            b[ni] = *(const short8*)&Bs[(wn + ni * 16 + lane16) * 32 + quad * 8];
        #pragma unroll
        for (int mi = 0; mi < 4; ++mi)
            #pragma unroll
            for (int ni = 0; ni < 4; ++ni)
                acc[mi][ni] = __builtin_amdgcn_mfma_f32_16x16x32_bf16(
                    a[mi], b[ni], acc[mi][ni], 0, 0, 0);
        __syncthreads();
    }

    unsigned short* Cb = C + (long)z * c_zoff + m0 * ldc + n0;
    const float* bb = bias + (long)z * bias_zoff + n0;
    #pragma unroll
    for (int mi = 0; mi < 4; ++mi) {
        #pragma unroll
        for (int ni = 0; ni < 4; ++ni) {
            const int col = wn + ni * 16 + lane16;
            const float bv = bb[col];
            #pragma unroll
            for (int r = 0; r < 4; ++r) {
                const int row = wm + mi * 16 + quad * 4 + r;
                float v = acc[mi][ni][r] + bv;
                if (RELU) v = fmaxf(v, 0.0f);
                Cb[(long)row * ldc + col] = f2bf(v);
            }
        }
    }
}

// ---------------------------------------------------------------------------
// Gate layer 2 + softmax: gw[b][t][k] = softmax_k(gh[b][t]·W2[t] + b2[t])
// ---------------------------------------------------------------------------
__global__ __launch_bounds__(256) void gate2_softmax(
    const unsigned short* __restrict__ gh, const float* __restrict__ W2,
    const float* __restrict__ b2, float* __restrict__ gw)
{
    const int t = blockIdx.y;
    const long b0 = (long)blockIdx.x * 64;
    const int tid = threadIdx.x;
    __shared__ __align__(16) unsigned short ghs[64 * 256];
    __shared__ float ls[64 * 16];
    #pragma unroll
    for (int it = 0; it < 8; ++it) {
        int seg = it * 256 + tid;
        int row = seg >> 5;
        int col = (seg & 31) * 8;
        *(uint4*)&ghs[seg * 8] =
            *(const uint4*)&gh[(b0 + row) * (T_N * GH_N) + (long)t * GH_N + col];
    }
    __syncthreads();
    const float* W2t = W2 + (long)t * GH_N * K16;
    #pragma unroll
    for (int it = 0; it < 4; ++it) {
        int o = it * 256 + tid;
        int b = o >> 4, k = o & 15;
        float acc = b2[t * K16 + k];
        #pragma unroll 8
        for (int h = 0; h < GH_N; ++h)
            acc += bf2f(ghs[b * 256 + h]) * W2t[h * K16 + k];
        ls[o] = acc;
    }
    __syncthreads();
    if (tid < 64) {
        float m = -1e30f;
        #pragma unroll
        for (int k = 0; k < 16; ++k) m = fmaxf(m, ls[tid * 16 + k]);
        float e[16], s = 0.f;
        #pragma unroll
        for (int k = 0; k < 16; ++k) { e[k] = expf(ls[tid * 16 + k] - m); s += e[k]; }
        const float inv = 1.0f / s;
        float* gwp = gw + (b0 + tid) * (T_N * K16) + (long)t * K16;
        #pragma unroll
        for (int k = 0; k < 16; ++k) gwp[k] = e[k] * inv;
    }
}

// ---------------------------------------------------------------------------
// agg: aggb[t][b][e] = bf16( sum_k gw[b][t][k] * emb[b][k*256+e] )
// ---------------------------------------------------------------------------
__global__ __launch_bounds__(256) void agg_kernel(
    const unsigned short* __restrict__ emb, const float* __restrict__ gw,
    unsigned short* __restrict__ aggb, long bc)
{
    const long b = (long)blockIdx.x * 8 + (threadIdx.x >> 5);
    const int e0 = (threadIdx.x & 31) * 8;
    const unsigned short* er = emb + b * 4096 + e0;
    const float* gwr = gw + b * 48;
    float a0[8] = {}, a1[8] = {}, a2[8] = {};
    #pragma unroll
    for (int k = 0; k < 16; ++k) {
        short8 v = *(const short8*)(er + (long)k * 256);
        const float w0 = gwr[k], w1 = gwr[16 + k], w2 = gwr[32 + k];
        #pragma unroll
        for (int j = 0; j < 8; ++j) {
            float f = bf2f((unsigned short)v[j]);
            a0[j] += w0 * f; a1[j] += w1 * f; a2[j] += w2 * f;
        }
    }
    unsigned r0[4] = {pack2(a0[0], a0[1]), pack2(a0[2], a0[3]),
                      pack2(a0[4], a0[5]), pack2(a0[6], a0[7])};
    unsigned r1[4] = {pack2(a1[0], a1[1]), pack2(a1[2], a1[3]),
                      pack2(a1[4], a1[5]), pack2(a1[6], a1[7])};
    unsigned r2[4] = {pack2(a2[0], a2[1]), pack2(a2[2], a2[3]),
                      pack2(a2[4], a2[5]), pack2(a2[6], a2[7])};
    *(uint4*)(aggb + 0L * bc * 256 + b * 256 + e0) = *(uint4*)r0;
    *(uint4*)(aggb + 1L * bc * 256 + b * 256 + e0) = *(uint4*)r1;
    *(uint4*)(aggb + 2L * bc * 256 + b * 256 + e0) = *(uint4*)r2;
}

// ---------------------------------------------------------------------------
// tower_fused (per t): th = relu(agg·W1+b1) [MFMA], out = th·W2+b2 [MFMA]
// ---------------------------------------------------------------------------
__global__ __launch_bounds__(256) void tower_fused(
    const unsigned short* __restrict__ aggb, long bc,
    const unsigned short* __restrict__ w1t, const float* __restrict__ tb1,
    const unsigned short* __restrict__ w2t, const float* __restrict__ tb2,
    float* __restrict__ out)
{
    __shared__ __align__(16) unsigned short sm[24576];   // 48 KB
    unsigned short* As  = sm;            // [128*32]   (stage 1 staging)
    unsigned short* Bs  = sm + 4096;     // [128*32]
    unsigned short* th  = sm;            // [128*128]  (reused after stage 1)
    unsigned short* w2s = sm + 16384;    // [64*128]
    const int tid = threadIdx.x;
    const int t = blockIdx.y;
    const long m0 = (long)blockIdx.x * 128;
    const unsigned short* Ab = aggb + (long)t * bc * 256 + m0 * 256;
    const unsigned short* Bb = w1t + (long)t * (TH_N * E_N);
    const int lane16 = tid & 15;
    const int quad = (tid & 63) >> 4;
    const int wave = tid >> 6;
    const int wm = (wave >> 1) * 64;
    const int wn = (wave & 1) * 64;
    const int srow = tid >> 2;
    const int scol = (tid & 3) * 8;

    #pragma unroll
    for (int i = 0; i < 4; ++i)
        *(uint4*)&w2s[(i * 256 + tid) * 8] =
            *(const uint4*)&w2t[(long)t * (TO_N * TH_N) + (long)(i * 256 + tid) * 8];

    floatx4 acc[4][4] = {};
    for (int k0 = 0; k0 < 256; k0 += 32) {
#if HAVE_GLL
        load_lds16(Ab + (long)srow * 256 + k0 + scol, &As[tid * 8]);
        load_lds16(Ab + (long)(srow + 64) * 256 + k0 + scol, &As[2048 + tid * 8]);
        load_lds16(Bb + (long)srow * 256 + k0 + scol, &Bs[tid * 8]);
        load_lds16(Bb + (long)(srow + 64) * 256 + k0 + scol, &Bs[2048 + tid * 8]);
#else
        *(uint4*)&As[tid * 8] = *(const uint4*)(Ab + (long)srow * 256 + k0 + scol);
        *(uint4*)&As[2048 + tid * 8] = *(const uint4*)(Ab + (long)(srow + 64) * 256 + k0 + scol);
        *(uint4*)&Bs[tid * 8] = *(const uint4*)(Bb + (long)srow * 256 + k0 + scol);
        *(uint4*)&Bs[2048 + tid * 8] = *(const uint4*)(Bb + (long)(srow + 64) * 256 + k0 + scol);
#endif
        __syncthreads();
        short8 a[4], b[4];
        #pragma unroll
        for (int mi = 0; mi < 4; ++mi)
            a[mi] = *(const short8*)&As[(wm + mi * 16 + lane16) * 32 + quad * 8];
        #pragma unroll
        for (int ni = 0; ni < 4; ++ni)
            b[ni] = *(const short8*)&Bs[(wn + ni * 16 + lane16) * 32 + quad * 8];
        #pragma unroll
        for (int mi = 0; mi < 4; ++mi)
            #pragma unroll
            for (int ni = 0; ni < 4; ++ni)
                acc[mi][ni] = __builtin_amdgcn_mfma_f32_16x16x32_bf16(
                    a[mi], b[ni], acc[mi][ni], 0, 0, 0);
        __syncthreads();
    }

    #pragma unroll
    for (int mi = 0; mi < 4; ++mi) {
        #pragma unroll
        for (int ni = 0; ni < 4; ++ni) {
            const int col = wn + ni * 16 + lane16;
            const float bv = tb1[t * TH_N + col];
            #pragma unroll
            for (int r = 0; r < 4; ++r) {
                const int row = wm + mi * 16 + quad * 4 + r;
                th[row * 128 + col] = f2bf(fmaxf(acc[mi][ni][r] + bv, 0.0f));
            }
        }
    }
    __syncthreads();

    floatx4 acc2[2][4] = {};
    #pragma unroll
    for (int kk = 0; kk < 4; ++kk) {
        short8 a2[2], b2[4];
        #pragma unroll
        for (int mi = 0; mi < 2; ++mi)
            a2[mi] = *(const short8*)&th[(wave * 32 + mi * 16 + lane16) * 128 + kk * 32 + quad * 8];
        #pragma unroll
        for (int ni = 0; ni < 4; ++ni)
            b2[ni] = *(const short8*)&w2s[(ni * 16 + lane16) * 128 + kk * 32 + quad * 8];
        #pragma unroll
        for (int mi = 0; mi < 2; ++mi)
            #pragma unroll
            for (int ni = 0; ni < 4; ++ni)
                acc2[mi][ni] = __builtin_amdgcn_mfma_f32_16x16x32_bf16(
                    a2[mi], b2[ni], acc2[mi][ni], 0, 0, 0);
    }
    #pragma unroll
    for (int mi = 0; mi < 2; ++mi) {
        #pragma unroll
        for (int ni = 0; ni < 4; ++ni) {
            const int col = ni * 16 + lane16;
            const float bv = tb2[t * TO_N + col];
            #pragma unroll
            for (int r = 0; r < 4; ++r) {
                const int row = wave * 32 + mi * 16 + quad * 4 + r;
                out[(m0 + row) * (T_N * TO_N) + t * TO_N + col] = acc2[mi][ni][r] + bv;
            }
        }
    }
}

// ---------------------------------------------------------------------------
extern "C" void kernel_launch(void* const* d_in, const int* in_sizes, int n_in,
                              void* d_out, int out_size, void* d_ws, size_t ws_size,
                              hipStream_t stream)
{
    const float* x   = (const float*)d_in[0];
    const float* eW1 = (const float*)d_in[1];
    const float* eb1 = (const float*)d_in[2];
    const float* eW2 = (const float*)d_in[3];
    const float* eb2 = (const float*)d_in[4];
    const float* gW1 = (const float*)d_in[5];
    const float* gb1 = (const float*)d_in[6];
    const float* gW2 = (const float*)d_in[7];
    const float* gb2 = (const float*)d_in[8];
    const float* tW1 = (const float*)d_in[9];
    const float* tb1 = (const float*)d_in[10];
    const float* tW2 = (const float*)d_in[11];
    const float* tb2 = (const float*)d_in[12];
    float* out = (float*)d_out;

    char* ws = (char*)d_ws;
    // Persistent weight buffers (bf16, transposed): 13,615,104 B total
    unsigned short* W1t  = (unsigned short*)(ws + 0);          // [16][512][512]
    unsigned short* W2t  = (unsigned short*)(ws + 8388608);    // [16][256][512]
    unsigned short* G1t  = (unsigned short*)(ws + 12582912);   // [3][256][512]
    unsigned short* TW1t = (unsigned short*)(ws + 13369344);   // [3][128][256]
    unsigned short* TW2t = (unsigned short*)(ws + 13565952);   // [3][64][128]
    const size_t WFIX = 13615104;

    // Per-chunk scratch: 18,624 B per batch row (no h1 anymore).
    const long per_row = 18624;
    long BC = 0;
    for (long cand = 16384; cand >= 256; cand >>= 1) {
        if (WFIX + (size_t)(cand * per_row) <= ws_size) { BC = cand; break; }
    }
    if (BC == 0) return;  // workspace too small — fail cleanly

    char* p = ws + WFIX;
    unsigned short* xb   = (unsigned short*)p; p += BC * 2048 * 2;  // [BC][G*D]
    unsigned short* ginb = (unsigned short*)p; p += BC * 1536 * 2;  // [BC][T*D]
    unsigned short* embb = (unsigned short*)p; p += BC * 4096 * 2;  // [BC][16*E]
    unsigned short* gh   = (unsigned short*)p; p += BC * 768 * 2;   // [BC][T*GH]
    float*          gw   = (float*)p;          p += BC * 48 * 4;    // [BC][T][16]
    unsigned short* aggb = (unsigned short*)p;                      // [3][BC][256]

    // Weight transposes (once per call)
    transpose_w<<<dim3(16, 16, 16), dim3(32, 8), 0, stream>>>(eW1, W1t, 512, 512);
    transpose_w<<<dim3(8, 16, 16), dim3(32, 8), 0, stream>>>(eW2, W2t, 512, 256);
    transpose_w<<<dim3(8, 16, 3), dim3(32, 8), 0, stream>>>(gW1, G1t, 512, 256);
    transpose_w<<<dim3(4, 8, 3), dim3(32, 8), 0, stream>>>(tW1, TW1t, 256, 128);
    transpose_w<<<dim3(2, 4, 3), dim3(32, 8), 0, stream>>>(tW2, TW2t, 128, 64);

    const long n_chunks = B_N / BC;
    for (long c = 0; c < n_chunks; ++c) {
        const float* xc = x + c * BC * (G_N * D_N);
        float* outc = out + c * BC * (T_N * TO_N);

        convert_inputs<<<BC, 256, 0, stream>>>(xc, xb, ginb);
        // fused expert L1+L2 -> emb (bf16)
        expert_fused<<<dim3(BC / 128, 16), 256, 0, stream>>>(
            xb, W1t, eb1, W2t, eb2, embb);
        // gate layer 1: per t: [BC x 512] @ [512 x 256] -> relu -> gh (bf16)
        gemm_bf16<1><<<dim3(BC / 128, 2, 3), 256, 0, stream>>>(
            ginb, 1536, 512, G1t, 131072, gb1, 256, gh, 768, 256, 512);
        // gate layer 2 + softmax -> gw (fp32)
        gate2_softmax<<<dim3(BC / 64, 3), 256, 0, stream>>>(gh, gW2, gb2, gw);
        // agg -> aggb bf16 [3][BC][256]
        agg_kernel<<<BC / 8, 256, 0, stream>>>(embb, gw, aggb, BC);
        // towers (MFMA, fused both layers) -> out fp32
        tower_fused<<<dim3(BC / 128, 3), 256, 0, stream>>>(
            aggb, BC, TW1t, tb1, TW2t, tb2, outc);
    }
}

// Round 5
// 763.261 us; speedup vs baseline: 1.2450x; 1.2450x over previous
//
#include <hip/hip_runtime.h>
#include <math.h>

// Problem constants (fixed by the reference)
#define B_N  16384
#define T_N  3
#define D_N  512
#define G_N  4
#define NE_N 4
#define H_N  512
#define E_N  256
#define GH_N 256
#define K16  16      // G*NE experts
#define TH_N 128
#define TO_N 64

typedef __attribute__((ext_vector_type(8))) short short8;
typedef __attribute__((ext_vector_type(4))) float floatx4;

__device__ __forceinline__ unsigned short f2bf(float f) {
    union { float f; unsigned u; } v; v.f = f;
    unsigned r = (v.u + 0x7fffu + ((v.u >> 16) & 1u)) >> 16;
    return (unsigned short)r;
}
__device__ __forceinline__ float bf2f(unsigned short h) {
    union { unsigned u; float f; } v; v.u = ((unsigned)h) << 16;
    return v.f;
}
__device__ __forceinline__ unsigned pack2(float lo, float hi) {
    return ((unsigned)f2bf(hi) << 16) | (unsigned)f2bf(lo);
}

typedef const __attribute__((address_space(1))) void gvoid_t;
typedef __attribute__((address_space(3))) void lvoid_t;

#if __has_builtin(__builtin_amdgcn_global_load_lds)
#define HAVE_GLL 1
__device__ __forceinline__ void load_lds16(const void* g, void* l) {
    __builtin_amdgcn_global_load_lds((gvoid_t*)g, (lvoid_t*)l, 16, 0, 0);
}
#else
#define HAVE_GLL 0
#endif

// ---------------------------------------------------------------------------
// Input cast: x -> bf16 [BC][G*D]; gin = x[:,1+t]+x[:,0] -> bf16 [BC][T*D]
// ---------------------------------------------------------------------------
__global__ __launch_bounds__(256) void convert_inputs(
    const float* __restrict__ x, unsigned short* __restrict__ xb,
    unsigned short* __restrict__ ginb)
{
    const long b = blockIdx.x;
    const int tid = threadIdx.x;           // 256 threads, 2 floats each per g
    const float* xr = x + b * (G_N * D_N);
    unsigned short* xo = xb + b * (G_N * D_N);
    unsigned short* go = ginb + b * (T_N * D_N);
    float2 v0 = *(const float2*)&xr[tid * 2];
    *(unsigned*)&xo[tid * 2] = pack2(v0.x, v0.y);
    #pragma unroll
    for (int g = 1; g < G_N; ++g) {
        float2 v = *(const float2*)&xr[g * D_N + tid * 2];
        *(unsigned*)&xo[g * D_N + tid * 2] = pack2(v.x, v.y);
        *(unsigned*)&go[(g - 1) * D_N + tid * 2] = pack2(v.x + v0.x, v.y + v0.y);
    }
}

// ---------------------------------------------------------------------------
// Weight transpose + cast: in fp32 [Z][K][N] -> out bf16 [Z][N][K]
// ---------------------------------------------------------------------------
__global__ __launch_bounds__(256) void transpose_w(
    const float* __restrict__ in, unsigned short* __restrict__ out, int K, int N)
{
    __shared__ float tile[32][33];
    const int tx = threadIdx.x, ty = threadIdx.y;      // block (32,8)
    const long zo = (long)blockIdx.z * K * N;
    const int n0 = blockIdx.x * 32, k0 = blockIdx.y * 32;
    #pragma unroll
    for (int i = 0; i < 4; ++i)
        tile[ty + 8 * i][tx] = in[zo + (long)(k0 + ty + 8 * i) * N + n0 + tx];
    __syncthreads();
    #pragma unroll
    for (int i = 0; i < 4; ++i)
        out[zo + (long)(n0 + ty + 8 * i) * K + k0 + tx] = f2bf(tile[tx][ty + 8 * i]);
}

// ---------------------------------------------------------------------------
// bf16 MFMA GEMM: C[z] = act(A[z] (MxK) * Bt[z]^T (N-major NxK) + bias[z])
// 128x128 tile, BK=64 (two BK=32 half-buffers -> 32 MFMAs per barrier pair),
// 256 threads = 4 waves (2x2 of 64x64). K must be a multiple of 64.
// ---------------------------------------------------------------------------
template<int RELU>
__global__ __launch_bounds__(256) void gemm_bf16(
    const unsigned short* __restrict__ A, int lda, int a_zoff,
    const unsigned short* __restrict__ Bt, int bt_zoff,
    const float* __restrict__ bias, int bias_zoff,
    unsigned short* __restrict__ C, int ldc, int c_zoff, int K)
{
    __shared__ __align__(16) unsigned short As[2][128 * 32];
    __shared__ __align__(16) unsigned short Bs[2][128 * 32];
    const int tid = threadIdx.x;
    const int z = blockIdx.z;
    const long m0 = (long)blockIdx.x * 128;
    const long n0 = (long)blockIdx.y * 128;
    const unsigned short* Ab = A + (long)z * a_zoff + m0 * lda;
    const unsigned short* Bb = Bt + (long)z * bt_zoff + n0 * K;
    const int lane16 = tid & 15;
    const int quad = (tid & 63) >> 4;
    const int wave = tid >> 6;
    const int wm = (wave >> 1) * 64;
    const int wn = (wave & 1) * 64;
    const int srow = tid >> 2;             // staging row (0..63)
    const int scol = (tid & 3) * 8;        // staging col (0,8,16,24)

    floatx4 acc[4][4] = {};

    for (int k0 = 0; k0 < K; k0 += 64) {
        #pragma unroll
        for (int h = 0; h < 2; ++h) {
            const int kh = k0 + h * 32;
#if HAVE_GLL
            load_lds16(Ab + (long)srow * lda + kh + scol, &As[h][tid * 8]);
            load_lds16(Ab + (long)(srow + 64) * lda + kh + scol, &As[h][2048 + tid * 8]);
            load_lds16(Bb + (long)srow * K + kh + scol, &Bs[h][tid * 8]);
            load_lds16(Bb + (long)(srow + 64) * K + kh + scol, &Bs[h][2048 + tid * 8]);
#else
            *(uint4*)&As[h][tid * 8] = *(const uint4*)(Ab + (long)srow * lda + kh + scol);
            *(uint4*)&As[h][2048 + tid * 8] = *(const uint4*)(Ab + (long)(srow + 64) * lda + kh + scol);
            *(uint4*)&Bs[h][tid * 8] = *(const uint4*)(Bb + (long)srow * K + kh + scol);
            *(uint4*)&Bs[h][2048 + tid * 8] = *(const uint4*)(Bb + (long)(srow + 64) * K + kh + scol);
#endif
        }
        __syncthreads();
        #pragma unroll
        for (int h = 0; h < 2; ++h) {
            short8 a[4], b[4];
            #pragma unroll
            for (int mi = 0; mi < 4; ++mi)
                a[mi] = *(const short8*)&As[h][(wm + mi * 16 + lane16) * 32 + quad * 8];
            #pragma unroll
            for (int ni = 0; ni < 4; ++ni)
                b[ni] = *(const short8*)&Bs[h][(wn + ni * 16 + lane16) * 32 + quad * 8];
            #pragma unroll
            for (int mi = 0; mi < 4; ++mi)
                #pragma unroll
                for (int ni = 0; ni < 4; ++ni)
                    acc[mi][ni] = __builtin_amdgcn_mfma_f32_16x16x32_bf16(
                        a[mi], b[ni], acc[mi][ni], 0, 0, 0);
        }
        __syncthreads();
    }

    unsigned short* Cb = C + (long)z * c_zoff + m0 * ldc + n0;
    const float* bb = bias + (long)z * bias_zoff + n0;
    #pragma unroll
    for (int mi = 0; mi < 4; ++mi) {
        #pragma unroll
        for (int ni = 0; ni < 4; ++ni) {
            const int col = wn + ni * 16 + lane16;
            const float bv = bb[col];
            #pragma unroll
            for (int r = 0; r < 4; ++r) {
                const int row = wm + mi * 16 + quad * 4 + r;
                float v = acc[mi][ni][r] + bv;
                if (RELU) v = fmaxf(v, 0.0f);
                Cb[(long)row * ldc + col] = f2bf(v);
            }
        }
    }
}

// ---------------------------------------------------------------------------
// Gate layer 2 + softmax: gw[b][t][k] = softmax_k(gh[b][t]·W2[t] + b2[t])
// ---------------------------------------------------------------------------
__global__ __launch_bounds__(256) void gate2_softmax(
    const unsigned short* __restrict__ gh, const float* __restrict__ W2,
    const float* __restrict__ b2, float* __restrict__ gw)
{
    const int t = blockIdx.y;
    const long b0 = (long)blockIdx.x * 64;
    const int tid = threadIdx.x;
    __shared__ __align__(16) unsigned short ghs[64 * 256];
    __shared__ float ls[64 * 16];
    #pragma unroll
    for (int it = 0; it < 8; ++it) {
        int seg = it * 256 + tid;
        int row = seg >> 5;
        int col = (seg & 31) * 8;
        *(uint4*)&ghs[seg * 8] =
            *(const uint4*)&gh[(b0 + row) * (T_N * GH_N) + (long)t * GH_N + col];
    }
    __syncthreads();
    const float* W2t = W2 + (long)t * GH_N * K16;
    #pragma unroll
    for (int it = 0; it < 4; ++it) {
        int o = it * 256 + tid;
        int b = o >> 4, k = o & 15;
        float acc = b2[t * K16 + k];
        #pragma unroll 8
        for (int h = 0; h < GH_N; ++h)
            acc += bf2f(ghs[b * 256 + h]) * W2t[h * K16 + k];
        ls[o] = acc;
    }
    __syncthreads();
    if (tid < 64) {
        float m = -1e30f;
        #pragma unroll
        for (int k = 0; k < 16; ++k) m = fmaxf(m, ls[tid * 16 + k]);
        float e[16], s = 0.f;
        #pragma unroll
        for (int k = 0; k < 16; ++k) { e[k] = expf(ls[tid * 16 + k] - m); s += e[k]; }
        const float inv = 1.0f / s;
        float* gwp = gw + (b0 + tid) * (T_N * K16) + (long)t * K16;
        #pragma unroll
        for (int k = 0; k < 16; ++k) gwp[k] = e[k] * inv;
    }
}

// ---------------------------------------------------------------------------
// agg: aggb[t][b][e] = bf16( sum_k gw[b][t][k] * emb[b][k*256+e] )
// ---------------------------------------------------------------------------
__global__ __launch_bounds__(256) void agg_kernel(
    const unsigned short* __restrict__ emb, const float* __restrict__ gw,
    unsigned short* __restrict__ aggb, long bc)
{
    const long b = (long)blockIdx.x * 8 + (threadIdx.x >> 5);
    const int e0 = (threadIdx.x & 31) * 8;
    const unsigned short* er = emb + b * 4096 + e0;
    const float* gwr = gw + b * 48;
    float a0[8] = {}, a1[8] = {}, a2[8] = {};
    #pragma unroll
    for (int k = 0; k < 16; ++k) {
        short8 v = *(const short8*)(er + (long)k * 256);
        const float w0 = gwr[k], w1 = gwr[16 + k], w2 = gwr[32 + k];
        #pragma unroll
        for (int j = 0; j < 8; ++j) {
            float f = bf2f((unsigned short)v[j]);
            a0[j] += w0 * f; a1[j] += w1 * f; a2[j] += w2 * f;
        }
    }
    unsigned r0[4] = {pack2(a0[0], a0[1]), pack2(a0[2], a0[3]),
                      pack2(a0[4], a0[5]), pack2(a0[6], a0[7])};
    unsigned r1[4] = {pack2(a1[0], a1[1]), pack2(a1[2], a1[3]),
                      pack2(a1[4], a1[5]), pack2(a1[6], a1[7])};
    unsigned r2[4] = {pack2(a2[0], a2[1]), pack2(a2[2], a2[3]),
                      pack2(a2[4], a2[5]), pack2(a2[6], a2[7])};
    *(uint4*)(aggb + 0L * bc * 256 + b * 256 + e0) = *(uint4*)r0;
    *(uint4*)(aggb + 1L * bc * 256 + b * 256 + e0) = *(uint4*)r1;
    *(uint4*)(aggb + 2L * bc * 256 + b * 256 + e0) = *(uint4*)r2;
}

// ---------------------------------------------------------------------------
// tower_fused (per t): th = relu(agg·W1+b1) [MFMA], out = th·W2+b2 [MFMA]
// ---------------------------------------------------------------------------
__global__ __launch_bounds__(256) void tower_fused(
    const unsigned short* __restrict__ aggb, long bc,
    const unsigned short* __restrict__ w1t, const float* __restrict__ tb1,
    const unsigned short* __restrict__ w2t, const float* __restrict__ tb2,
    float* __restrict__ out)
{
    __shared__ __align__(16) unsigned short sm[24576];   // 48 KB
    unsigned short* As  = sm;            // [128*32]   (stage 1 staging)
    unsigned short* Bs  = sm + 4096;     // [128*32]
    unsigned short* th  = sm;            // [128*128]  (reused after stage 1)
    unsigned short* w2s = sm + 16384;    // [64*128]
    const int tid = threadIdx.x;
    const int t = blockIdx.y;
    const long m0 = (long)blockIdx.x * 128;
    const unsigned short* Ab = aggb + (long)t * bc * 256 + m0 * 256;
    const unsigned short* Bb = w1t + (long)t * (TH_N * E_N);
    const int lane16 = tid & 15;
    const int quad = (tid & 63) >> 4;
    const int wave = tid >> 6;
    const int wm = (wave >> 1) * 64;
    const int wn = (wave & 1) * 64;
    const int srow = tid >> 2;
    const int scol = (tid & 3) * 8;

    #pragma unroll
    for (int i = 0; i < 4; ++i)
        *(uint4*)&w2s[(i * 256 + tid) * 8] =
            *(const uint4*)&w2t[(long)t * (TO_N * TH_N) + (long)(i * 256 + tid) * 8];

    floatx4 acc[4][4] = {};
    for (int k0 = 0; k0 < 256; k0 += 32) {
#if HAVE_GLL
        load_lds16(Ab + (long)srow * 256 + k0 + scol, &As[tid * 8]);
        load_lds16(Ab + (long)(srow + 64) * 256 + k0 + scol, &As[2048 + tid * 8]);
        load_lds16(Bb + (long)srow * 256 + k0 + scol, &Bs[tid * 8]);
        load_lds16(Bb + (long)(srow + 64) * 256 + k0 + scol, &Bs[2048 + tid * 8]);
#else
        *(uint4*)&As[tid * 8] = *(const uint4*)(Ab + (long)srow * 256 + k0 + scol);
        *(uint4*)&As[2048 + tid * 8] = *(const uint4*)(Ab + (long)(srow + 64) * 256 + k0 + scol);
        *(uint4*)&Bs[tid * 8] = *(const uint4*)(Bb + (long)srow * 256 + k0 + scol);
        *(uint4*)&Bs[2048 + tid * 8] = *(const uint4*)(Bb + (long)(srow + 64) * 256 + k0 + scol);
#endif
        __syncthreads();
        short8 a[4], b[4];
        #pragma unroll
        for (int mi = 0; mi < 4; ++mi)
            a[mi] = *(const short8*)&As[(wm + mi * 16 + lane16) * 32 + quad * 8];
        #pragma unroll
        for (int ni = 0; ni < 4; ++ni)
            b[ni] = *(const short8*)&Bs[(wn + ni * 16 + lane16) * 32 + quad * 8];
        #pragma unroll
        for (int mi = 0; mi < 4; ++mi)
            #pragma unroll
            for (int ni = 0; ni < 4; ++ni)
                acc[mi][ni] = __builtin_amdgcn_mfma_f32_16x16x32_bf16(
                    a[mi], b[ni], acc[mi][ni], 0, 0, 0);
        __syncthreads();
    }

    #pragma unroll
    for (int mi = 0; mi < 4; ++mi) {
        #pragma unroll
        for (int ni = 0; ni < 4; ++ni) {
            const int col = wn + ni * 16 + lane16;
            const float bv = tb1[t * TH_N + col];
            #pragma unroll
            for (int r = 0; r < 4; ++r) {
                const int row = wm + mi * 16 + quad * 4 + r;
                th[row * 128 + col] = f2bf(fmaxf(acc[mi][ni][r] + bv, 0.0f));
            }
        }
    }
    __syncthreads();

    floatx4 acc2[2][4] = {};
    #pragma unroll
    for (int kk = 0; kk < 4; ++kk) {
        short8 a2[2], b2[4];
        #pragma unroll
        for (int mi = 0; mi < 2; ++mi)
            a2[mi] = *(const short8*)&th[(wave * 32 + mi * 16 + lane16) * 128 + kk * 32 + quad * 8];
        #pragma unroll
        for (int ni = 0; ni < 4; ++ni)
            b2[ni] = *(const short8*)&w2s[(ni * 16 + lane16) * 128 + kk * 32 + quad * 8];
        #pragma unroll
        for (int mi = 0; mi < 2; ++mi)
            #pragma unroll
            for (int ni = 0; ni < 4; ++ni)
                acc2[mi][ni] = __builtin_amdgcn_mfma_f32_16x16x32_bf16(
                    a2[mi], b2[ni], acc2[mi][ni], 0, 0, 0);
    }
    #pragma unroll
    for (int mi = 0; mi < 2; ++mi) {
        #pragma unroll
        for (int ni = 0; ni < 4; ++ni) {
            const int col = ni * 16 + lane16;
            const float bv = tb2[t * TO_N + col];
            #pragma unroll
            for (int r = 0; r < 4; ++r) {
                const int row = wave * 32 + mi * 16 + quad * 4 + r;
                out[(m0 + row) * (T_N * TO_N) + t * TO_N + col] = acc2[mi][ni][r] + bv;
            }
        }
    }
}

// ---------------------------------------------------------------------------
extern "C" void kernel_launch(void* const* d_in, const int* in_sizes, int n_in,
                              void* d_out, int out_size, void* d_ws, size_t ws_size,
                              hipStream_t stream)
{
    const float* x   = (const float*)d_in[0];
    const float* eW1 = (const float*)d_in[1];
    const float* eb1 = (const float*)d_in[2];
    const float* eW2 = (const float*)d_in[3];
    const float* eb2 = (const float*)d_in[4];
    const float* gW1 = (const float*)d_in[5];
    const float* gb1 = (const float*)d_in[6];
    const float* gW2 = (const float*)d_in[7];
    const float* gb2 = (const float*)d_in[8];
    const float* tW1 = (const float*)d_in[9];
    const float* tb1 = (const float*)d_in[10];
    const float* tW2 = (const float*)d_in[11];
    const float* tb2 = (const float*)d_in[12];
    float* out = (float*)d_out;

    char* ws = (char*)d_ws;
    // Persistent weight buffers (bf16, transposed): 13,615,104 B total
    unsigned short* W1t  = (unsigned short*)(ws + 0);          // [16][512][512]
    unsigned short* W2t  = (unsigned short*)(ws + 8388608);    // [16][256][512]
    unsigned short* G1t  = (unsigned short*)(ws + 12582912);   // [3][256][512]
    unsigned short* TW1t = (unsigned short*)(ws + 13369344);   // [3][128][256]
    unsigned short* TW2t = (unsigned short*)(ws + 13565952);   // [3][64][128]
    const size_t WFIX = 13615104;

    // Per-chunk scratch: 35,008 B per batch row; largest chunk that fits.
    const long per_row = 35008;
    long BC = 0;
    for (long cand = 16384; cand >= 256; cand >>= 1) {
        if (WFIX + (size_t)(cand * per_row) <= ws_size) { BC = cand; break; }
    }
    if (BC == 0) return;  // workspace too small — fail cleanly

    char* p = ws + WFIX;
    unsigned short* xb   = (unsigned short*)p; p += BC * 2048 * 2;  // [BC][G*D]
    unsigned short* ginb = (unsigned short*)p; p += BC * 1536 * 2;  // [BC][T*D]
    unsigned short* h1   = (unsigned short*)p; p += BC * 8192 * 2;  // [BC][16*H]
    unsigned short* embb = (unsigned short*)p; p += BC * 4096 * 2;  // [BC][16*E]
    unsigned short* gh   = (unsigned short*)p; p += BC * 768 * 2;   // [BC][T*GH]
    float*          gw   = (float*)p;          p += BC * 48 * 4;    // [BC][T][16]
    unsigned short* aggb = (unsigned short*)p;                      // [3][BC][256]

    // Weight transposes (once per call)
    transpose_w<<<dim3(16, 16, 16), dim3(32, 8), 0, stream>>>(eW1, W1t, 512, 512);
    transpose_w<<<dim3(8, 16, 16), dim3(32, 8), 0, stream>>>(eW2, W2t, 512, 256);
    transpose_w<<<dim3(8, 16, 3), dim3(32, 8), 0, stream>>>(gW1, G1t, 512, 256);
    transpose_w<<<dim3(4, 8, 3), dim3(32, 8), 0, stream>>>(tW1, TW1t, 256, 128);
    transpose_w<<<dim3(2, 4, 3), dim3(32, 8), 0, stream>>>(tW2, TW2t, 128, 64);

    const long n_chunks = B_N / BC;
    for (long c = 0; c < n_chunks; ++c) {
        const float* xc = x + c * BC * (G_N * D_N);
        float* outc = out + c * BC * (T_N * TO_N);

        convert_inputs<<<BC, 256, 0, stream>>>(xc, xb, ginb);
        // expert layer 1: per g: [BC x 512] @ [512 x 2048] -> relu -> h1 (bf16)
        gemm_bf16<1><<<dim3(BC / 128, 16, 4), 256, 0, stream>>>(
            xb, 2048, 512, W1t, 1048576, eb1, 2048, h1, 8192, 2048, 512);
        // gate layer 1: per t: [BC x 512] @ [512 x 256] -> relu -> gh (bf16)
        gemm_bf16<1><<<dim3(BC / 128, 2, 3), 256, 0, stream>>>(
            ginb, 1536, 512, G1t, 131072, gb1, 256, gh, 768, 256, 512);
        // gate layer 2 + softmax -> gw (fp32)
        gate2_softmax<<<dim3(BC / 64, 3), 256, 0, stream>>>(gh, gW2, gb2, gw);
        // expert layer 2: per (g,n): [BC x 512] @ [512 x 256] -> emb (bf16)
        gemm_bf16<0><<<dim3(BC / 128, 2, 16), 256, 0, stream>>>(
            h1, 8192, 512, W2t, 131072, eb2, 256, embb, 4096, 256, 512);
        // agg -> aggb bf16 [3][BC][256]
        agg_kernel<<<BC / 8, 256, 0, stream>>>(embb, gw, aggb, BC);
        // towers (MFMA, fused both layers) -> out fp32
        tower_fused<<<dim3(BC / 128, 3), 256, 0, stream>>>(
            aggb, BC, TW1t, tb1, TW2t, tb2, outc);
    }
}

// Round 6
// 709.827 us; speedup vs baseline: 1.3387x; 1.0753x over previous
//
#include <hip/hip_runtime.h>
#include <math.h>

// Problem constants (fixed by the reference)
#define B_N  16384
#define T_N  3
#define D_N  512
#define G_N  4
#define NE_N 4
#define H_N  512
#define E_N  256
#define GH_N 256
#define K16  16      // G*NE experts
#define TH_N 128
#define TO_N 64

typedef __attribute__((ext_vector_type(8))) short short8;
typedef __attribute__((ext_vector_type(4))) float floatx4;

__device__ __forceinline__ unsigned short f2bf(float f) {
    union { float f; unsigned u; } v; v.f = f;
    unsigned r = (v.u + 0x7fffu + ((v.u >> 16) & 1u)) >> 16;
    return (unsigned short)r;
}
__device__ __forceinline__ float bf2f(unsigned short h) {
    union { unsigned u; float f; } v; v.u = ((unsigned)h) << 16;
    return v.f;
}
__device__ __forceinline__ unsigned pack2(float lo, float hi) {
    return ((unsigned)f2bf(hi) << 16) | (unsigned)f2bf(lo);
}

typedef const __attribute__((address_space(1))) void gvoid_t;
typedef __attribute__((address_space(3))) void lvoid_t;

#if __has_builtin(__builtin_amdgcn_global_load_lds)
#define HAVE_GLL 1
__device__ __forceinline__ void load_lds16(const void* g, void* l) {
    __builtin_amdgcn_global_load_lds((gvoid_t*)g, (lvoid_t*)l, 16, 0, 0);
}
#else
#define HAVE_GLL 0
#endif

// ---------------------------------------------------------------------------
// Input cast: x -> bf16 [BC][G*D]; gin = x[:,1+t]+x[:,0] -> bf16 [BC][T*D]
// ---------------------------------------------------------------------------
__global__ __launch_bounds__(256) void convert_inputs(
    const float* __restrict__ x, unsigned short* __restrict__ xb,
    unsigned short* __restrict__ ginb)
{
    const long b = blockIdx.x;
    const int tid = threadIdx.x;           // 256 threads, 2 floats each per g
    const float* xr = x + b * (G_N * D_N);
    unsigned short* xo = xb + b * (G_N * D_N);
    unsigned short* go = ginb + b * (T_N * D_N);
    float2 v0 = *(const float2*)&xr[tid * 2];
    *(unsigned*)&xo[tid * 2] = pack2(v0.x, v0.y);
    #pragma unroll
    for (int g = 1; g < G_N; ++g) {
        float2 v = *(const float2*)&xr[g * D_N + tid * 2];
        *(unsigned*)&xo[g * D_N + tid * 2] = pack2(v.x, v.y);
        *(unsigned*)&go[(g - 1) * D_N + tid * 2] = pack2(v.x + v0.x, v.y + v0.y);
    }
}

// ---------------------------------------------------------------------------
// Weight transpose + cast: in fp32 [Z][K][N] -> out bf16 [Z][N][K]
// ---------------------------------------------------------------------------
__global__ __launch_bounds__(256) void transpose_w(
    const float* __restrict__ in, unsigned short* __restrict__ out, int K, int N)
{
    __shared__ float tile[32][33];
    const int tx = threadIdx.x, ty = threadIdx.y;      // block (32,8)
    const long zo = (long)blockIdx.z * K * N;
    const int n0 = blockIdx.x * 32, k0 = blockIdx.y * 32;
    #pragma unroll
    for (int i = 0; i < 4; ++i)
        tile[ty + 8 * i][tx] = in[zo + (long)(k0 + ty + 8 * i) * N + n0 + tx];
    __syncthreads();
    #pragma unroll
    for (int i = 0; i < 4; ++i)
        out[zo + (long)(n0 + ty + 8 * i) * K + k0 + tx] = f2bf(tile[tx][ty + 8 * i]);
}

// ---------------------------------------------------------------------------
// bf16 MFMA GEMM: C[z] = act(A[z] (MxK) * Bt[z]^T (N-major NxK) + bias[z])
// 128x128 tile, BK=64 (two BK=32 half-buffers), XOR-swizzled LDS layout:
//   staging thread (row sr = tid>>2) fetches global colblock (tid&3)^((sr>>1)&3)
//   fragment read uses colblock quad^((lane16>>1)&3)
// -> 2-way bank aliasing only (free). 256 threads = 4 waves (2x2 of 64x64).
// ---------------------------------------------------------------------------
template<int RELU>
__global__ __launch_bounds__(256) void gemm_bf16(
    const unsigned short* __restrict__ A, int lda, int a_zoff,
    const unsigned short* __restrict__ Bt, int bt_zoff,
    const float* __restrict__ bias, int bias_zoff,
    unsigned short* __restrict__ C, int ldc, int c_zoff, int K)
{
    __shared__ __align__(16) unsigned short As[2][128 * 32];
    __shared__ __align__(16) unsigned short Bs[2][128 * 32];
    const int tid = threadIdx.x;
    const int z = blockIdx.z;
    const long m0 = (long)blockIdx.x * 128;
    const long n0 = (long)blockIdx.y * 128;
    const unsigned short* Ab = A + (long)z * a_zoff + m0 * lda;
    const unsigned short* Bb = Bt + (long)z * bt_zoff + n0 * K;
    const int lane16 = tid & 15;
    const int quad = (tid & 63) >> 4;
    const int wave = tid >> 6;
    const int wm = (wave >> 1) * 64;
    const int wn = (wave & 1) * 64;
    const int srow = tid >> 2;                       // staging row (0..63)
    const int scolsw = (((tid & 3) ^ ((tid >> 3) & 3)) * 8);  // swizzled col
    const int cw8 = ((quad ^ ((lane16 >> 1) & 3)) * 8);       // frag read col

    floatx4 acc[4][4] = {};

    for (int k0 = 0; k0 < K; k0 += 64) {
        #pragma unroll
        for (int h = 0; h < 2; ++h) {
            const int kh = k0 + h * 32;
#if HAVE_GLL
            load_lds16(Ab + (long)srow * lda + kh + scolsw, &As[h][tid * 8]);
            load_lds16(Ab + (long)(srow + 64) * lda + kh + scolsw, &As[h][2048 + tid * 8]);
            load_lds16(Bb + (long)srow * K + kh + scolsw, &Bs[h][tid * 8]);
            load_lds16(Bb + (long)(srow + 64) * K + kh + scolsw, &Bs[h][2048 + tid * 8]);
#else
            *(uint4*)&As[h][tid * 8] = *(const uint4*)(Ab + (long)srow * lda + kh + scolsw);
            *(uint4*)&As[h][2048 + tid * 8] = *(const uint4*)(Ab + (long)(srow + 64) * lda + kh + scolsw);
            *(uint4*)&Bs[h][tid * 8] = *(const uint4*)(Bb + (long)srow * K + kh + scolsw);
            *(uint4*)&Bs[h][2048 + tid * 8] = *(const uint4*)(Bb + (long)(srow + 64) * K + kh + scolsw);
#endif
        }
        __syncthreads();
        #pragma unroll
        for (int h = 0; h < 2; ++h) {
            short8 a[4], b[4];
            #pragma unroll
            for (int mi = 0; mi < 4; ++mi)
                a[mi] = *(const short8*)&As[h][(wm + mi * 16 + lane16) * 32 + cw8];
            #pragma unroll
            for (int ni = 0; ni < 4; ++ni)
                b[ni] = *(const short8*)&Bs[h][(wn + ni * 16 + lane16) * 32 + cw8];
            #pragma unroll
            for (int mi = 0; mi < 4; ++mi)
                #pragma unroll
                for (int ni = 0; ni < 4; ++ni)
                    acc[mi][ni] = __builtin_amdgcn_mfma_f32_16x16x32_bf16(
                        a[mi], b[ni], acc[mi][ni], 0, 0, 0);
        }
        __syncthreads();
    }

    unsigned short* Cb = C + (long)z * c_zoff + m0 * ldc + n0;
    const float* bb = bias + (long)z * bias_zoff + n0;
    #pragma unroll
    for (int mi = 0; mi < 4; ++mi) {
        #pragma unroll
        for (int ni = 0; ni < 4; ++ni) {
            const int col = wn + ni * 16 + lane16;
            const float bv = bb[col];
            #pragma unroll
            for (int r = 0; r < 4; ++r) {
                const int row = wm + mi * 16 + quad * 4 + r;
                float v = acc[mi][ni][r] + bv;
                if (RELU) v = fmaxf(v, 0.0f);
                Cb[(long)row * ldc + col] = f2bf(v);
            }
        }
    }
}

// ---------------------------------------------------------------------------
// Gate layer 2 + softmax: gw[b][t][k] = softmax_k(gh[b][t]·W2[t] + b2[t])
// ---------------------------------------------------------------------------
__global__ __launch_bounds__(256) void gate2_softmax(
    const unsigned short* __restrict__ gh, const float* __restrict__ W2,
    const float* __restrict__ b2, float* __restrict__ gw)
{
    const int t = blockIdx.y;
    const long b0 = (long)blockIdx.x * 64;
    const int tid = threadIdx.x;
    __shared__ __align__(16) unsigned short ghs[64 * 256];
    __shared__ float ls[64 * 16];
    #pragma unroll
    for (int it = 0; it < 8; ++it) {
        int seg = it * 256 + tid;
        int row = seg >> 5;
        int col = (seg & 31) * 8;
        *(uint4*)&ghs[seg * 8] =
            *(const uint4*)&gh[(b0 + row) * (T_N * GH_N) + (long)t * GH_N + col];
    }
    __syncthreads();
    const float* W2t = W2 + (long)t * GH_N * K16;
    #pragma unroll
    for (int it = 0; it < 4; ++it) {
        int o = it * 256 + tid;
        int b = o >> 4, k = o & 15;
        float acc = b2[t * K16 + k];
        #pragma unroll 8
        for (int h = 0; h < GH_N; ++h)
            acc += bf2f(ghs[b * 256 + h]) * W2t[h * K16 + k];
        ls[o] = acc;
    }
    __syncthreads();
    if (tid < 64) {
        float m = -1e30f;
        #pragma unroll
        for (int k = 0; k < 16; ++k) m = fmaxf(m, ls[tid * 16 + k]);
        float e[16], s = 0.f;
        #pragma unroll
        for (int k = 0; k < 16; ++k) { e[k] = expf(ls[tid * 16 + k] - m); s += e[k]; }
        const float inv = 1.0f / s;
        float* gwp = gw + (b0 + tid) * (T_N * K16) + (long)t * K16;
        #pragma unroll
        for (int k = 0; k < 16; ++k) gwp[k] = e[k] * inv;
    }
}

// ---------------------------------------------------------------------------
// agg: aggb[t][b][e] = bf16( sum_k gw[b][t][k] * emb[b][k*256+e] )
// ---------------------------------------------------------------------------
__global__ __launch_bounds__(256) void agg_kernel(
    const unsigned short* __restrict__ emb, const float* __restrict__ gw,
    unsigned short* __restrict__ aggb, long bc)
{
    const long b = (long)blockIdx.x * 8 + (threadIdx.x >> 5);
    const int e0 = (threadIdx.x & 31) * 8;
    const unsigned short* er = emb + b * 4096 + e0;
    const float* gwr = gw + b * 48;
    float a0[8] = {}, a1[8] = {}, a2[8] = {};
    #pragma unroll
    for (int k = 0; k < 16; ++k) {
        short8 v = *(const short8*)(er + (long)k * 256);
        const float w0 = gwr[k], w1 = gwr[16 + k], w2 = gwr[32 + k];
        #pragma unroll
        for (int j = 0; j < 8; ++j) {
            float f = bf2f((unsigned short)v[j]);
            a0[j] += w0 * f; a1[j] += w1 * f; a2[j] += w2 * f;
        }
    }
    unsigned r0[4] = {pack2(a0[0], a0[1]), pack2(a0[2], a0[3]),
                      pack2(a0[4], a0[5]), pack2(a0[6], a0[7])};
    unsigned r1[4] = {pack2(a1[0], a1[1]), pack2(a1[2], a1[3]),
                      pack2(a1[4], a1[5]), pack2(a1[6], a1[7])};
    unsigned r2[4] = {pack2(a2[0], a2[1]), pack2(a2[2], a2[3]),
                      pack2(a2[4], a2[5]), pack2(a2[6], a2[7])};
    *(uint4*)(aggb + 0L * bc * 256 + b * 256 + e0) = *(uint4*)r0;
    *(uint4*)(aggb + 1L * bc * 256 + b * 256 + e0) = *(uint4*)r1;
    *(uint4*)(aggb + 2L * bc * 256 + b * 256 + e0) = *(uint4*)r2;
}

// ---------------------------------------------------------------------------
// tower_fused (per t): th = relu(agg·W1+b1) [MFMA], out = th·W2+b2 [MFMA]
// Stage-1 uses the swizzled staging; th/w2s padded to stride 136 (no 16-way
// conflicts on stage-2 reads).
// ---------------------------------------------------------------------------
__global__ __launch_bounds__(256) void tower_fused(
    const unsigned short* __restrict__ aggb, long bc,
    const unsigned short* __restrict__ w1t, const float* __restrict__ tb1,
    const unsigned short* __restrict__ w2t, const float* __restrict__ tb2,
    float* __restrict__ out)
{
    __shared__ __align__(16) unsigned short sm[26112];   // 52224 B
    unsigned short* As  = sm;            // [128*32]   (stage 1 staging)
    unsigned short* Bs  = sm + 4096;     // [128*32]
    unsigned short* th  = sm;            // [128*136]  (reused after stage 1)
    unsigned short* w2s = sm + 17408;    // [64*136]
    const int tid = threadIdx.x;
    const int t = blockIdx.y;
    const long m0 = (long)blockIdx.x * 128;
    const unsigned short* Ab = aggb + (long)t * bc * 256 + m0 * 256;
    const unsigned short* Bb = w1t + (long)t * (TH_N * E_N);
    const int lane16 = tid & 15;
    const int quad = (tid & 63) >> 4;
    const int wave = tid >> 6;
    const int wm = (wave >> 1) * 64;
    const int wn = (wave & 1) * 64;
    const int srow = tid >> 2;
    const int scolsw = (((tid & 3) ^ ((tid >> 3) & 3)) * 8);
    const int cw8 = ((quad ^ ((lane16 >> 1) & 3)) * 8);

    // W2 tile [64][128] bf16 -> padded w2s [64][136]
    #pragma unroll
    for (int i = 0; i < 4; ++i) {
        const int seg = i * 256 + tid;
        const int row = seg >> 4, cb = (seg & 15) * 8;
        *(uint4*)&w2s[row * 136 + cb] =
            *(const uint4*)&w2t[(long)t * (TO_N * TH_N) + (long)row * 128 + cb];
    }

    floatx4 acc[4][4] = {};
    for (int k0 = 0; k0 < 256; k0 += 32) {
#if HAVE_GLL
        load_lds16(Ab + (long)srow * 256 + k0 + scolsw, &As[tid * 8]);
        load_lds16(Ab + (long)(srow + 64) * 256 + k0 + scolsw, &As[2048 + tid * 8]);
        load_lds16(Bb + (long)srow * 256 + k0 + scolsw, &Bs[tid * 8]);
        load_lds16(Bb + (long)(srow + 64) * 256 + k0 + scolsw, &Bs[2048 + tid * 8]);
#else
        *(uint4*)&As[tid * 8] = *(const uint4*)(Ab + (long)srow * 256 + k0 + scolsw);
        *(uint4*)&As[2048 + tid * 8] = *(const uint4*)(Ab + (long)(srow + 64) * 256 + k0 + scolsw);
        *(uint4*)&Bs[tid * 8] = *(const uint4*)(Bb + (long)srow * 256 + k0 + scolsw);
        *(uint4*)&Bs[2048 + tid * 8] = *(const uint4*)(Bb + (long)(srow + 64) * 256 + k0 + scolsw);
#endif
        __syncthreads();
        short8 a[4], b[4];
        #pragma unroll
        for (int mi = 0; mi < 4; ++mi)
            a[mi] = *(const short8*)&As[(wm + mi * 16 + lane16) * 32 + cw8];
        #pragma unroll
        for (int ni = 0; ni < 4; ++ni)
            b[ni] = *(const short8*)&Bs[(wn + ni * 16 + lane16) * 32 + cw8];
        #pragma unroll
        for (int mi = 0; mi < 4; ++mi)
            #pragma unroll
            for (int ni = 0; ni < 4; ++ni)
                acc[mi][ni] = __builtin_amdgcn_mfma_f32_16x16x32_bf16(
                    a[mi], b[ni], acc[mi][ni], 0, 0, 0);
        __syncthreads();
    }

    #pragma unroll
    for (int mi = 0; mi < 4; ++mi) {
        #pragma unroll
        for (int ni = 0; ni < 4; ++ni) {
            const int col = wn + ni * 16 + lane16;
            const float bv = tb1[t * TH_N + col];
            #pragma unroll
            for (int r = 0; r < 4; ++r) {
                const int row = wm + mi * 16 + quad * 4 + r;
                th[row * 136 + col] = f2bf(fmaxf(acc[mi][ni][r] + bv, 0.0f));
            }
        }
    }
    __syncthreads();

    floatx4 acc2[2][4] = {};
    #pragma unroll
    for (int kk = 0; kk < 4; ++kk) {
        short8 a2[2], b2[4];
        #pragma unroll
        for (int mi = 0; mi < 2; ++mi)
            a2[mi] = *(const short8*)&th[(wave * 32 + mi * 16 + lane16) * 136 + kk * 32 + quad * 8];
        #pragma unroll
        for (int ni = 0; ni < 4; ++ni)
            b2[ni] = *(const short8*)&w2s[(ni * 16 + lane16) * 136 + kk * 32 + quad * 8];
        #pragma unroll
        for (int mi = 0; mi < 2; ++mi)
            #pragma unroll
            for (int ni = 0; ni < 4; ++ni)
                acc2[mi][ni] = __builtin_amdgcn_mfma_f32_16x16x32_bf16(
                    a2[mi], b2[ni], acc2[mi][ni], 0, 0, 0);
    }
    #pragma unroll
    for (int mi = 0; mi < 2; ++mi) {
        #pragma unroll
        for (int ni = 0; ni < 4; ++ni) {
            const int col = ni * 16 + lane16;
            const float bv = tb2[t * TO_N + col];
            #pragma unroll
            for (int r = 0; r < 4; ++r) {
                const int row = wave * 32 + mi * 16 + quad * 4 + r;
                out[(m0 + row) * (T_N * TO_N) + t * TO_N + col] = acc2[mi][ni][r] + bv;
            }
        }
    }
}

// ---------------------------------------------------------------------------
extern "C" void kernel_launch(void* const* d_in, const int* in_sizes, int n_in,
                              void* d_out, int out_size, void* d_ws, size_t ws_size,
                              hipStream_t stream)
{
    const float* x   = (const float*)d_in[0];
    const float* eW1 = (const float*)d_in[1];
    const float* eb1 = (const float*)d_in[2];
    const float* eW2 = (const float*)d_in[3];
    const float* eb2 = (const float*)d_in[4];
    const float* gW1 = (const float*)d_in[5];
    const float* gb1 = (const float*)d_in[6];
    const float* gW2 = (const float*)d_in[7];
    const float* gb2 = (const float*)d_in[8];
    const float* tW1 = (const float*)d_in[9];
    const float* tb1 = (const float*)d_in[10];
    const float* tW2 = (const float*)d_in[11];
    const float* tb2 = (const float*)d_in[12];
    float* out = (float*)d_out;

    char* ws = (char*)d_ws;
    // Persistent weight buffers (bf16, transposed): 13,615,104 B total
    unsigned short* W1t  = (unsigned short*)(ws + 0);          // [16][512][512]
    unsigned short* W2t  = (unsigned short*)(ws + 8388608);    // [16][256][512]
    unsigned short* G1t  = (unsigned short*)(ws + 12582912);   // [3][256][512]
    unsigned short* TW1t = (unsigned short*)(ws + 13369344);   // [3][128][256]
    unsigned short* TW2t = (unsigned short*)(ws + 13565952);   // [3][64][128]
    const size_t WFIX = 13615104;

    // Adaptive chunking: BCo rows for base buffers (18,624 B/row),
    // BCh rows for the h1 intermediate (16,384 B/row). Prefer BCh >= BCo/2.
    long BCo = 0, BCh = 0;
    {
        long bestCo = 0, bestCh = 0;
        for (long co = 16384; co >= 256; co >>= 1) {
            size_t base = WFIX + (size_t)co * 18624;
            if (base + (size_t)128 * 16384 > ws_size) continue;
            long ch = 0;
            for (long c = co; c >= 128; c >>= 1)
                if (base + (size_t)c * 16384 <= ws_size) { ch = c; break; }
            if (ch * 2 >= co) { bestCo = co; bestCh = ch; break; }
            if (ch > bestCh) { bestCo = co; bestCh = ch; }
        }
        BCo = bestCo; BCh = bestCh;
    }
    if (BCo == 0) return;  // workspace too small — fail cleanly

    char* p = ws + WFIX;
    unsigned short* xb   = (unsigned short*)p; p += BCo * 4096;  // [BCo][G*D]
    unsigned short* ginb = (unsigned short*)p; p += BCo * 3072;  // [BCo][T*D]
    unsigned short* embb = (unsigned short*)p; p += BCo * 8192;  // [BCo][16*E]
    unsigned short* gh   = (unsigned short*)p; p += BCo * 1536;  // [BCo][T*GH]
    float*          gw   = (float*)p;          p += BCo * 192;   // [BCo][T][16]
    unsigned short* aggb = (unsigned short*)p; p += BCo * 1536;  // [3][BCo][256]
    unsigned short* h1   = (unsigned short*)p;                   // [BCh][16*H]

    // Weight transposes (once per call)
    transpose_w<<<dim3(16, 16, 16), dim3(32, 8), 0, stream>>>(eW1, W1t, 512, 512);
    transpose_w<<<dim3(8, 16, 16), dim3(32, 8), 0, stream>>>(eW2, W2t, 512, 256);
    transpose_w<<<dim3(8, 16, 3), dim3(32, 8), 0, stream>>>(gW1, G1t, 512, 256);
    transpose_w<<<dim3(4, 8, 3), dim3(32, 8), 0, stream>>>(tW1, TW1t, 256, 128);
    transpose_w<<<dim3(2, 4, 3), dim3(32, 8), 0, stream>>>(tW2, TW2t, 128, 64);

    const long n_o = B_N / BCo;
    for (long c = 0; c < n_o; ++c) {
        const float* xc = x + c * BCo * (G_N * D_N);
        float* outc = out + c * BCo * (T_N * TO_N);

        convert_inputs<<<BCo, 256, 0, stream>>>(xc, xb, ginb);
        // gate layer 1: per t: [BCo x 512] @ [512 x 256] -> relu -> gh (bf16)
        gemm_bf16<1><<<dim3(BCo / 128, 2, 3), 256, 0, stream>>>(
            ginb, 1536, 512, G1t, 131072, gb1, 256, gh, 768, 256, 512);
        // gate layer 2 + softmax -> gw (fp32)
        gate2_softmax<<<dim3(BCo / 64, 3), 256, 0, stream>>>(gh, gW2, gb2, gw);
        // expert layers, h1-chunked
        for (long d = 0; d < BCo / BCh; ++d) {
            gemm_bf16<1><<<dim3(BCh / 128, 16, 4), 256, 0, stream>>>(
                xb + d * BCh * 2048, 2048, 512, W1t, 1048576, eb1, 2048,
                h1, 8192, 2048, 512);
            gemm_bf16<0><<<dim3(BCh / 128, 2, 16), 256, 0, stream>>>(
                h1, 8192, 512, W2t, 131072, eb2, 256,
                embb + d * BCh * 4096, 4096, 256, 512);
        }
        // agg -> aggb bf16 [3][BCo][256]
        agg_kernel<<<BCo / 8, 256, 0, stream>>>(embb, gw, aggb, BCo);
        // towers (MFMA, fused both layers) -> out fp32
        tower_fused<<<dim3(BCo / 128, 3), 256, 0, stream>>>(
            aggb, BCo, TW1t, tb1, TW2t, tb2, outc);
    }
}